// Round 6
// baseline (616.254 us; speedup 1.0000x reference)
//
#include <hip/hip_runtime.h>

// SNN classifier: h_all = x @ W1^T + b1 via in-register f16 split-2 MFMA
// (3 GEMM terms, fp32-grade accuracy), then LIF scan over T=25.
//   x  [B=128, T=25, F=12288] f32 ; W1 [2048, 12288] ; Wo [2,2048]
// Split per element (in-register, after LDS read of raw fp32):
//   a = ah + al (f16 RNE + residual), w*128 = bh + bl;  h*128 = ah*bh + ah*bl + al*bh.
//
// GEMM: 256x256 tile, 512 thr (8 waves 2Mx4N), wave-tile 128x64 of 32x32x16
// MFMA frags. No conversion kernels: fp32 x/W staged directly via per-lane
// -source global_load_lds into a [row][slot^(row&7)] 128B-row LDS image
// (source pre-swizzle, rule #21; conflict-free ds_read_b128 proven r2-r5).
// PERSISTENT balanced schedule: 104 tiles x 384 kt = 39936 units, 256 blocks
// x 156 units; partials to slot (swz - floor(384*mnt/156)) of 4 buffers.
// LIF: phase 1 = 256 blocks (b x hid-half, independent dynamics) reducing
// 3-4 slots + Wo partial sums; phase 2 = 1 block output-membrane scan.

#define T_STEPS 25
#define B_SZ    128
#define F_SZ    12288
#define HID_SZ  2048
#define KT      384
#define M_PAD   3328           // 13 * 256
#define UPB     156            // units per block = 104*384/256
#define PART_STRIDE ((size_t)M_PAD * HID_SZ)

typedef __attribute__((ext_vector_type(8))) _Float16 f16x8;
typedef __attribute__((ext_vector_type(4))) float f32x4;
typedef __attribute__((ext_vector_type(16))) float f32x16;

__device__ __forceinline__ void g2l16(const void* g, void* l) {
  __builtin_amdgcn_global_load_lds(
      (const __attribute__((address_space(1))) void*)g,
      (__attribute__((address_space(3))) void*)l, 16, 0, 0);
}

// 8 fp32 -> f16 hi (RNE) + f16 residual lo; sc=128 for W keeps lo f16-normal
__device__ __forceinline__ void split8(f32x4 v0, f32x4 v1,
                                       f16x8& hi, f16x8& lo, float sc) {
#pragma unroll
  for (int j = 0; j < 4; ++j) {
    float a = v0[j] * sc;
    _Float16 h = (_Float16)a;
    hi[j] = h;
    lo[j] = (_Float16)(a - (float)h);
    float b = v1[j] * sc;
    _Float16 h2 = (_Float16)b;
    hi[4 + j] = h2;
    lo[4 + j] = (_Float16)(b - (float)h2);
  }
}

// ---- persistent MFMA GEMM: direct fp32 staging, in-reg split, 32x32x16 ----
__global__ __launch_bounds__(512, 1) void gemm_persist_kernel(
    const float* __restrict__ x, const float* __restrict__ W1,
    float* __restrict__ parts) {
  __shared__ __align__(16) char lds[131072];  // 2 x (A 32K | B 32K)
  const int tid = threadIdx.x;
  const int l = tid & 63;
  const int w = tid >> 6;      // wave 0..7
  const int wm = w >> 2;       // 0..1 : rows wm*128
  const int wn = w & 3;        // 0..3 : cols wn*64

  // XCD-aware bijective swizzle (256 = 8 XCDs * 32)
  const int swz = ((blockIdx.x & 7) << 5) + (blockIdx.x >> 3);

  // staging constants: lane covers (row = i*64 + tid>>3, dest slot = tid&7);
  // source slot pre-XORed with row&7 so the LDS image is [row][slot^(row&7)]
  const int srow = tid >> 3;                        // 0..63
  const int sof = (((tid & 7) ^ (srow & 7)) << 4);  // swizzled src byte off

  // fragment-read constants
  const int lxor = l & 7;
  const int klo = (l >> 5) * 2;                 // k-half -> slot pair base
  const int arow = (wm * 128 + (l & 31)) * 128; // A image row byte base
  const int brow = (wn * 64 + (l & 31)) * 128;  // B image row byte base

  int u = swz * UPB;
  const int u1 = u + UPB;

  while (u < u1) {
    const int mnt = u / 384;
    const int kt0 = u - mnt * 384;
    const int rem_t = 384 - kt0, rem_u = u1 - u;
    const int seg = rem_t < rem_u ? rem_t : rem_u;
    const int ktN = kt0 + seg;
    const int mt = mnt >> 3;
    const int nt = mnt & 7;

    // per-issue source row base pointers (pre-offset by swizzled slot)
    int pm0 = mt * 256 + 0 * 64 + srow; pm0 = pm0 > 3199 ? 3199 : pm0;
    int pm1 = mt * 256 + 1 * 64 + srow; pm1 = pm1 > 3199 ? 3199 : pm1;
    int pm2 = mt * 256 + 2 * 64 + srow; pm2 = pm2 > 3199 ? 3199 : pm2;
    int pm3 = mt * 256 + 3 * 64 + srow; pm3 = pm3 > 3199 ? 3199 : pm3;
    const char* aB0 = (const char*)(x + ((size_t)((pm0 & 127) * T_STEPS + (pm0 >> 7))) * F_SZ) + sof;
    const char* aB1 = (const char*)(x + ((size_t)((pm1 & 127) * T_STEPS + (pm1 >> 7))) * F_SZ) + sof;
    const char* aB2 = (const char*)(x + ((size_t)((pm2 & 127) * T_STEPS + (pm2 >> 7))) * F_SZ) + sof;
    const char* aB3 = (const char*)(x + ((size_t)((pm3 & 127) * T_STEPS + (pm3 >> 7))) * F_SZ) + sof;
    const char* bB0 = (const char*)(W1 + (size_t)(nt * 256 +   0 + srow) * F_SZ) + sof;
    const char* bB1 = (const char*)(W1 + (size_t)(nt * 256 +  64 + srow) * F_SZ) + sof;
    const char* bB2 = (const char*)(W1 + (size_t)(nt * 256 + 128 + srow) * F_SZ) + sof;
    const char* bB3 = (const char*)(W1 + (size_t)(nt * 256 + 192 + srow) * F_SZ) + sof;

#define STAGE(ktx)                                                     \
    do {                                                               \
      char* d_ = (char*)lds + ((ktx) & 1) * 65536 + tid * 16;          \
      const int ko_ = (ktx) * 128;                                     \
      g2l16(aB0 + ko_, d_);         g2l16(bB0 + ko_, d_ + 32768);      \
      g2l16(aB1 + ko_, d_ + 8192);  g2l16(bB1 + ko_, d_ + 40960);      \
      g2l16(aB2 + ko_, d_ + 16384); g2l16(bB2 + ko_, d_ + 49152);      \
      g2l16(aB3 + ko_, d_ + 24576); g2l16(bB3 + ko_, d_ + 57344);      \
    } while (0)

    f32x16 acc[4][2];
#pragma unroll
    for (int i = 0; i < 4; ++i)
#pragma unroll
      for (int j = 0; j < 2; ++j)
#pragma unroll
        for (int r = 0; r < 16; ++r) acc[i][j][r] = 0.f;

    STAGE(kt0);  // segment prologue

    for (int kt = kt0; kt < ktN; ++kt) {
      __syncthreads();             // drains stage(kt), issued a tile earlier
      if (kt + 1 < ktN) STAGE(kt + 1);

      const char* la = (const char*)lds + (kt & 1) * 65536;
      const char* lb = la + 32768;

#pragma unroll
      for (int ks = 0; ks < 2; ++ks) {
        const int s0 = ks * 4 + klo;
        const int o0 = (s0 ^ lxor) << 4;
        const int o1 = ((s0 + 1) ^ lxor) << 4;
        f16x8 ah[4], al[4];
#pragma unroll
        for (int mf = 0; mf < 4; ++mf) {
          f32x4 v0 = *(const f32x4*)(la + arow + mf * 4096 + o0);
          f32x4 v1 = *(const f32x4*)(la + arow + mf * 4096 + o1);
          split8(v0, v1, ah[mf], al[mf], 1.0f);
        }
#pragma unroll
        for (int nf = 0; nf < 2; ++nf) {
          f32x4 u0 = *(const f32x4*)(lb + brow + nf * 4096 + o0);
          f32x4 u1 = *(const f32x4*)(lb + brow + nf * 4096 + o1);
          f16x8 bh, bl;
          split8(u0, u1, bh, bl, 128.0f);
          __builtin_amdgcn_s_setprio(1);
#pragma unroll
          for (int mf = 0; mf < 4; ++mf) {
            acc[mf][nf] = __builtin_amdgcn_mfma_f32_32x32x16_f16(ah[mf], bh, acc[mf][nf], 0, 0, 0);
            acc[mf][nf] = __builtin_amdgcn_mfma_f32_32x32x16_f16(ah[mf], bl, acc[mf][nf], 0, 0, 0);
            acc[mf][nf] = __builtin_amdgcn_mfma_f32_32x32x16_f16(al[mf], bh, acc[mf][nf], 0, 0, 0);
          }
          __builtin_amdgcn_s_setprio(0);
        }
      }
    }

    // epilogue: raw partials. 32x32 C/D: col=l&31, row=(r&3)+8*(r>>2)+4*(l>>5)
    const int slot = swz - (mnt * 384) / UPB;
    float* dst = parts + (size_t)slot * PART_STRIDE;
    const int row0 = mt * 256 + wm * 128 + ((l >> 5) << 2);
    const int col0 = nt * 256 + wn * 64 + (l & 31);
#pragma unroll
    for (int nf = 0; nf < 2; ++nf)
#pragma unroll
      for (int mf = 0; mf < 4; ++mf)
#pragma unroll
        for (int r = 0; r < 16; ++r) {
          const int row = row0 + mf * 32 + (r & 3) + ((r >> 2) << 3);
          dst[(size_t)row * HID_SZ + col0 + nf * 32] = acc[mf][nf][r];
        }
    u += seg;
    __syncthreads();  // LDS quiet before next segment's STAGE
#undef STAGE
  }
}

// ---- fallback fp32 vector GEMM (used only if ws tiny); writes biased h ----
__global__ __launch_bounds__(256) void gemm_h_kernel(
    const float* __restrict__ x, const float* __restrict__ W1,
    const float* __restrict__ b1, float* __restrict__ h_all) {
  __shared__ float As[16][128];
  __shared__ float Bs[16][128];
  const int tid = threadIdx.x;
  const int tx = tid & 15;
  const int ty = tid >> 4;
  const int m0 = blockIdx.x * 128;
  const int n0 = blockIdx.y * 128;
  const int lrow = tid >> 1;
  const int lcol = (tid & 1) * 8;
  const int gm = m0 + lrow;
  const int bb = gm & (B_SZ - 1);
  const int tt = gm >> 7;
  const float* aptr = x + ((size_t)bb * T_STEPS + tt) * F_SZ + lcol;
  const float* bptr = W1 + (size_t)(n0 + lrow) * F_SZ + lcol;
  float acc[8][8];
#pragma unroll
  for (int i = 0; i < 8; ++i)
#pragma unroll
    for (int j = 0; j < 8; ++j) acc[i][j] = 0.f;
  for (int k0 = 0; k0 < F_SZ; k0 += 16) {
    float4 av0 = *(const float4*)(aptr + k0);
    float4 av1 = *(const float4*)(aptr + k0 + 4);
    float4 bv0 = *(const float4*)(bptr + k0);
    float4 bv1 = *(const float4*)(bptr + k0 + 4);
    As[lcol + 0][lrow] = av0.x; As[lcol + 1][lrow] = av0.y;
    As[lcol + 2][lrow] = av0.z; As[lcol + 3][lrow] = av0.w;
    As[lcol + 4][lrow] = av1.x; As[lcol + 5][lrow] = av1.y;
    As[lcol + 6][lrow] = av1.z; As[lcol + 7][lrow] = av1.w;
    Bs[lcol + 0][lrow] = bv0.x; Bs[lcol + 1][lrow] = bv0.y;
    Bs[lcol + 2][lrow] = bv0.z; Bs[lcol + 3][lrow] = bv0.w;
    Bs[lcol + 4][lrow] = bv1.x; Bs[lcol + 5][lrow] = bv1.y;
    Bs[lcol + 6][lrow] = bv1.z; Bs[lcol + 7][lrow] = bv1.w;
    __syncthreads();
#pragma unroll
    for (int k = 0; k < 16; ++k) {
      float4 a0 = *(const float4*)&As[k][ty * 8];
      float4 a1 = *(const float4*)&As[k][ty * 8 + 4];
      float4 q0 = *(const float4*)&Bs[k][tx * 8];
      float4 q1 = *(const float4*)&Bs[k][tx * 8 + 4];
      float ar[8] = {a0.x, a0.y, a0.z, a0.w, a1.x, a1.y, a1.z, a1.w};
      float br[8] = {q0.x, q0.y, q0.z, q0.w, q1.x, q1.y, q1.z, q1.w};
#pragma unroll
      for (int i = 0; i < 8; ++i)
#pragma unroll
        for (int j = 0; j < 8; ++j)
          acc[i][j] = fmaf(ar[i], br[j], acc[i][j]);
    }
    __syncthreads();
  }
#pragma unroll
  for (int i = 0; i < 8; ++i) {
    const int gm2 = m0 + ty * 8 + i;
    float* orow = h_all + (size_t)gm2 * HID_SZ + n0 + tx * 8;
    const float* brow = b1 + n0 + tx * 8;
#pragma unroll
    for (int j = 0; j < 8; ++j) orow[j] = acc[i][j] + brow[j];
  }
}

// ---- LIF phase 1: hidden-layer dynamics + Wo partial sums ------------------
// 256 blocks = (b 0..127) x (half 0..1); each block owns 1024 hidden units.
// mode 2: reduce 3-4 persistent slots; mode 0: parts[0] is prebiased h.
__global__ __launch_bounds__(256) void lif_hidden_kernel(
    const float* __restrict__ parts, const float* __restrict__ b1,
    const float* __restrict__ Wo, float* __restrict__ oc, int mode) {
  const int b = blockIdx.x & 127;
  const int half = blockIdx.x >> 7;
  const int tid = threadIdx.x;
  const int h0 = half * 1024;
  float mem1[4], wo0[4], wo1[4], bv[4];
#pragma unroll
  for (int i = 0; i < 4; ++i) {
    const int hid = h0 + 256 * i + tid;
    mem1[i] = 0.f;
    wo0[i] = Wo[hid];
    wo1[i] = Wo[HID_SZ + hid];
    bv[i] = b1[hid];
  }
  __shared__ float partial[4][2];
  for (int t = 0; t < T_STEPS; ++t) {
    const int row = t * B_SZ + b;
    const size_t rowb = (size_t)row * HID_SZ;
    const int mt8 = (row >> 8) * 8;
    float pr0 = 0.f, pr1 = 0.f;
#pragma unroll
    for (int i = 0; i < 4; ++i) {
      const int hid = h0 + 256 * i + tid;
      const size_t idx = rowb + hid;
      float h;
      if (mode == 2) {
        float s = parts[idx] + parts[idx + PART_STRIDE] +
                  parts[idx + 2 * PART_STRIDE];
        const int k0 = (mt8 + (hid >> 8)) * 384;
        if ((k0 + 383) / UPB - k0 / UPB + 1 == 4)
          s += parts[idx + 3 * PART_STRIDE];
        h = s * 0.0078125f + bv[i];
      } else {
        h = parts[idx];
      }
      float r1 = mem1[i] > 1.0f ? 1.0f : 0.0f;
      float m = 0.9f * mem1[i] + h - r1;
      mem1[i] = m;
      if (m > 1.0f) { pr0 += wo0[i]; pr1 += wo1[i]; }
    }
#pragma unroll
    for (int off = 32; off > 0; off >>= 1) {
      pr0 += __shfl_down(pr0, off);
      pr1 += __shfl_down(pr1, off);
    }
    if ((tid & 63) == 0) { partial[tid >> 6][0] = pr0; partial[tid >> 6][1] = pr1; }
    __syncthreads();
    if (tid == 0) {
      const size_t o = (((size_t)b * 2 + half) * T_STEPS + t) * 2;
      oc[o + 0] = partial[0][0] + partial[1][0] + partial[2][0] + partial[3][0];
      oc[o + 1] = partial[0][1] + partial[1][1] + partial[2][1] + partial[3][1];
    }
    __syncthreads();
  }
}

// ---- LIF phase 2: output-layer membrane scan + spike count -----------------
__global__ __launch_bounds__(128) void lif_out_kernel(
    const float* __restrict__ oc, const float* __restrict__ bo,
    float* __restrict__ out) {
  const int b = threadIdx.x;
  float memo0 = 0.f, memo1 = 0.f, a0 = 0.f, a1 = 0.f;
  const float bo0 = bo[0], bo1 = bo[1];
  for (int t = 0; t < T_STEPS; ++t) {
    const size_t i0 = (((size_t)b * 2 + 0) * T_STEPS + t) * 2;
    const size_t i1 = (((size_t)b * 2 + 1) * T_STEPS + t) * 2;
    float o0 = oc[i0] + oc[i1] + bo0;
    float o1 = oc[i0 + 1] + oc[i1 + 1] + bo1;
    float ro0 = memo0 > 1.0f ? 1.0f : 0.0f;
    float ro1 = memo1 > 1.0f ? 1.0f : 0.0f;
    memo0 = 0.9f * memo0 + o0 - ro0;
    memo1 = 0.9f * memo1 + o1 - ro1;
    a0 += memo0 > 1.0f ? 1.0f : 0.0f;
    a1 += memo1 > 1.0f ? 1.0f : 0.0f;
  }
  out[b * 2 + 0] = a0;
  out[b * 2 + 1] = a1;
}

extern "C" void kernel_launch(void* const* d_in, const int* in_sizes, int n_in,
                              void* d_out, int out_size, void* d_ws, size_t ws_size,
                              hipStream_t stream) {
  const float* x  = (const float*)d_in[0];
  const float* W1 = (const float*)d_in[1];
  const float* b1 = (const float*)d_in[2];
  const float* Wo = (const float*)d_in[3];
  const float* bo = (const float*)d_in[4];
  float* out = (float*)d_out;

  const size_t part_bytes = PART_STRIDE * 4;                 // 27.26 MB
  const size_t oc_bytes = (size_t)128 * 2 * T_STEPS * 2 * 4; // 51.2 KB
  char* ws = (char*)d_ws;
  float* parts = (float*)ws;

  if (ws_size >= 4 * part_bytes + oc_bytes) {
    float* oc = (float*)(ws + 4 * part_bytes);
    gemm_persist_kernel<<<256, 512, 0, stream>>>(x, W1, parts);
    lif_hidden_kernel<<<256, 256, 0, stream>>>(parts, b1, Wo, oc, 2);
    lif_out_kernel<<<1, 128, 0, stream>>>(oc, bo, out);
  } else {
    float* oc = (float*)(ws + part_bytes);
    dim3 grid(25, 16);
    gemm_h_kernel<<<grid, 256, 0, stream>>>(x, W1, b1, parts);
    lif_hidden_kernel<<<256, 256, 0, stream>>>(parts, b1, Wo, oc, 0);
    lif_out_kernel<<<1, 128, 0, stream>>>(oc, bo, out);
  }
}